// Round 1
// baseline (741.984 us; speedup 1.0000x reference)
//
#include <hip/hip_runtime.h>

typedef unsigned short u16;
typedef __bf16 bf16x8 __attribute__((ext_vector_type(8)));
typedef float f32x4 __attribute__((ext_vector_type(4)));
typedef u16 u16x4 __attribute__((ext_vector_type(4)));

__device__ __forceinline__ u16 f2bf(float f) {
    unsigned u = __float_as_uint(f);
    unsigned r = (u + 0x7FFFu + ((u >> 16) & 1u)) >> 16;
    return (u16)r;
}
__device__ __forceinline__ float bf2f(u16 h) {
    return __uint_as_float(((unsigned)h) << 16);
}

// ---------------------------------------------------------------- stats ----
// grid (B*C, 2); y==0 -> tensor c, y==1 -> tensor s. 4096 elems per row.
__global__ void __launch_bounds__(256) stats_kernel(
    const float* __restrict__ c, const float* __restrict__ s,
    float* __restrict__ mC, float* __restrict__ rC,
    float* __restrict__ mS, float* __restrict__ rS)
{
    const float* src = (blockIdx.y ? s : c) + (size_t)blockIdx.x * 4096;
    int t = threadIdx.x, lane = t & 63, wv = t >> 6;
    const float4* p = (const float4*)src;
    float sum = 0.f, sq = 0.f;
#pragma unroll
    for (int i = 0; i < 4; ++i) {
        float4 v = p[t + 256 * i];
        sum += v.x + v.y + v.z + v.w;
        sq  += v.x * v.x + v.y * v.y + v.z * v.z + v.w * v.w;
    }
#pragma unroll
    for (int m = 1; m < 64; m <<= 1) {
        sum += __shfl_xor(sum, m);
        sq  += __shfl_xor(sq, m);
    }
    __shared__ float sa[4], sb[4];
    if (!lane) { sa[wv] = sum; sb[wv] = sq; }
    __syncthreads();
    if (t == 0) {
        float S = sa[0] + sa[1] + sa[2] + sa[3];
        float Q = sb[0] + sb[1] + sb[2] + sb[3];
        float mean = S * (1.0f / 4096.0f);
        float var = (Q - 4096.0f * mean * mean) * (1.0f / 4095.0f);
        float rstd = rsqrtf(var + 1e-5f);
        if (blockIdx.y) { mS[blockIdx.x] = mean; rS[blockIdx.x] = rstd; }
        else            { mC[blockIdx.x] = mean; rC[blockIdx.x] = rstd; }
    }
}

// ------------------------------------------------------- transpose pack ----
// [B,C,N] fp32 -> [B,N,C] bf16 (hi/lo if MODE==0 with instancenorm, plain if 1)
template<int MODE>
__global__ void __launch_bounds__(256) pack_kernel(
    const float* __restrict__ src, const float* __restrict__ mean,
    const float* __restrict__ rstd, u16* __restrict__ dh, u16* __restrict__ dl)
{
    __shared__ float tile[32][33];
    int b = blockIdx.z, n0 = blockIdx.x * 32, c0 = blockIdx.y * 32;
    int tx = threadIdx.x, ty = threadIdx.y;
    const float* sbp = src + ((size_t)b * 512 + c0) * 4096 + n0;
#pragma unroll
    for (int it = 0; it < 4; ++it)
        tile[ty + it * 8][tx] = sbp[(size_t)(ty + it * 8) * 4096 + tx];
    __syncthreads();
    int ch = c0 + tx;
    float mn = 0.f, rs = 1.f;
    if (MODE == 0) { mn = mean[b * 512 + ch]; rs = rstd[b * 512 + ch]; }
    size_t obase = ((size_t)b * 4096 + n0) * 512 + c0;
#pragma unroll
    for (int it = 0; it < 4; ++it) {
        int r = ty + it * 8;
        float v = tile[tx][r];
        if (MODE == 0) v = (v - mn) * rs;
        u16 h = f2bf(v);
        dh[obase + (size_t)r * 512 + tx] = h;
        if (MODE == 0) dl[obase + (size_t)r * 512 + tx] = f2bf(v - bf2f(h));
    }
}

// ------------------------------------------------------------ wt split ----
template<bool LO>
__global__ void __launch_bounds__(256) split_hilo(
    const float* __restrict__ src, u16* __restrict__ h, u16* __restrict__ l, int n)
{
    int i = blockIdx.x * 256 + threadIdx.x;
    if (i < n) {
        float v = src[i];
        u16 a = f2bf(v);
        h[i] = a;
        if (LO) l[i] = f2bf(v - bf2f(a));
    }
}

// ---------------------------------------------------------------- GEMM ----
// C[i,j] = sum_t sum_k A_t[i,k]*B_t[j,k]  (A:[M,K] rowmajor, B:[N,K] rowmajor)
// NT==3: hi/lo compensated ( AhBh + AhBl + AlBh ).
#define EPI_F32        0
#define EPI_T_HILO     1
#define EPI_PLAIN_BF16 2
#define EPI_T_BF16     3
#define EPI_OUT        4

__device__ __forceinline__ void stage_tile(
    const u16* __restrict__ g, int ldk, int i0, int k0, char* tile, int wv, int lane)
{
#pragma unroll
    for (int cc = 0; cc < 4; ++cc) {
        int chunk = (wv * 4 + cc) * 64 + lane;   // 16B-chunk linear index in tile
        int row  = chunk >> 3;                   // 8 chunks (128B) per row
        int slot = chunk & 7;
        int gc   = slot ^ (row & 7);             // pre-swizzled source column-chunk
        const u16* gp = g + (size_t)(i0 + row) * ldk + (k0 + gc * 8);
        char* lp = tile + (size_t)(wv * 4 + cc) * 1024; // wave-uniform base
        __builtin_amdgcn_global_load_lds(
            (const __attribute__((address_space(1))) unsigned int*)gp,
            (__attribute__((address_space(3))) unsigned int*)lp, 16, 0, 0);
    }
}

template<int NT, int EPI>
__global__ void __launch_bounds__(256) gemm_bt(
    const u16* __restrict__ Ah_, const u16* __restrict__ Al_,
    const u16* __restrict__ Bh_, const u16* __restrict__ Bl_,
    int K, const float* __restrict__ bias,
    float* __restrict__ outF_, u16* __restrict__ outH_, u16* __restrict__ outL_,
    const float* __restrict__ resid_, int ldo,
    long aB, long bB, long oB, long rB)
{
    constexpr int NTILES = (NT == 3) ? 4 : 2;
    __shared__ char smem[NTILES * 16384];
    char* sAh = smem;
    char* sBh = smem + 16384;
    char* sAl = smem + 32768;
    char* sBl = smem + 49152;

    int bz = blockIdx.z;
    const u16* A  = Ah_ + (size_t)bz * aB;
    const u16* Bm = Bh_ + (size_t)bz * bB;
    const u16* A2 = (NT == 3) ? Al_ + (size_t)bz * aB : nullptr;
    const u16* B2 = (NT == 3) ? Bl_ + (size_t)bz * bB : nullptr;

    int i0 = blockIdx.y * 128, j0 = blockIdx.x * 128;
    int tid = threadIdx.x, lane = tid & 63, wv = tid >> 6;
    int wr = wv >> 1, wc = wv & 1;
    int r15 = lane & 15, h4 = lane >> 4;

    f32x4 zero = {0.f, 0.f, 0.f, 0.f};
    f32x4 acc[4][4];
#pragma unroll
    for (int m = 0; m < 4; ++m)
#pragma unroll
        for (int n = 0; n < 4; ++n) acc[m][n] = zero;

    for (int k0 = 0; k0 < K; k0 += 64) {
        stage_tile(A, K, i0, k0, sAh, wv, lane);
        stage_tile(Bm, K, j0, k0, sBh, wv, lane);
        if constexpr (NT == 3) {
            stage_tile(A2, K, i0, k0, sAl, wv, lane);
            stage_tile(B2, K, j0, k0, sBl, wv, lane);
        }
        asm volatile("s_waitcnt vmcnt(0)" ::: "memory");
        __syncthreads();
#pragma unroll
        for (int ks = 0; ks < 2; ++ks) {
            bf16x8 ah[4], bh[4], al[4], bl[4];
#pragma unroll
            for (int m = 0; m < 4; ++m) {
                int row = wr * 64 + m * 16 + r15;
                int off = row * 128 + (((ks * 4 + h4) ^ (row & 7)) << 4);
                ah[m] = *(const bf16x8*)(sAh + off);
                if constexpr (NT == 3) al[m] = *(const bf16x8*)(sAl + off);
            }
#pragma unroll
            for (int n = 0; n < 4; ++n) {
                int col = wc * 64 + n * 16 + r15;
                int off = col * 128 + (((ks * 4 + h4) ^ (col & 7)) << 4);
                bh[n] = *(const bf16x8*)(sBh + off);
                if constexpr (NT == 3) bl[n] = *(const bf16x8*)(sBl + off);
            }
#pragma unroll
            for (int m = 0; m < 4; ++m)
#pragma unroll
                for (int n = 0; n < 4; ++n) {
                    acc[m][n] = __builtin_amdgcn_mfma_f32_16x16x32_bf16(ah[m], bh[n], acc[m][n], 0, 0, 0);
                    if constexpr (NT == 3) {
                        acc[m][n] = __builtin_amdgcn_mfma_f32_16x16x32_bf16(ah[m], bl[n], acc[m][n], 0, 0, 0);
                        acc[m][n] = __builtin_amdgcn_mfma_f32_16x16x32_bf16(al[m], bh[n], acc[m][n], 0, 0, 0);
                    }
                }
        }
        __syncthreads();
    }

    float* outF = outF_ ? outF_ + (size_t)bz * oB : nullptr;
    u16* outH = outH_ ? outH_ + (size_t)bz * oB : nullptr;
    u16* outL = outL_ ? outL_ + (size_t)bz * oB : nullptr;
    const float* resid = resid_ ? resid_ + (size_t)bz * rB : nullptr;

#pragma unroll
    for (int m = 0; m < 4; ++m)
#pragma unroll
        for (int n = 0; n < 4; ++n) {
            int ibase = i0 + wr * 64 + m * 16 + h4 * 4;
            int j = j0 + wc * 64 + n * 16 + r15;
#pragma unroll
            for (int r = 0; r < 4; ++r) {
                int i = ibase + r;
                float v = acc[m][n][r];
                if constexpr (EPI == EPI_T_HILO || EPI == EPI_PLAIN_BF16 || EPI == EPI_OUT)
                    v += bias[i];
                if constexpr (EPI == EPI_F32) {
                    outF[(size_t)i * ldo + j] = v;
                } else if constexpr (EPI == EPI_T_HILO) {
                    size_t o = (size_t)j * ldo + i;
                    u16 h = f2bf(v);
                    outH[o] = h;
                    outL[o] = f2bf(v - bf2f(h));
                } else if constexpr (EPI == EPI_PLAIN_BF16) {
                    outH[(size_t)i * ldo + j] = f2bf(v);
                } else if constexpr (EPI == EPI_T_BF16) {
                    outH[(size_t)j * ldo + i] = f2bf(v);
                } else { // EPI_OUT
                    outF[(size_t)i * ldo + j] = v + resid[(size_t)i * ldo + j];
                }
            }
        }
}

// ------------------------------------------------------------- softmax ----
// one block per row; L row fp32[4096] -> P row bf16[4096] (softmax over m)
__global__ void __launch_bounds__(256) softmax_kernel(
    const float* __restrict__ L, u16* __restrict__ P)
{
    int row = blockIdx.x;
    int t = threadIdx.x, lane = t & 63, wv = t >> 6;
    const float4* src = (const float4*)(L + (size_t)row * 4096);
    float4 v[4];
    float mx = -3.4e38f;
#pragma unroll
    for (int i = 0; i < 4; ++i) {
        v[i] = src[t + 256 * i];
        mx = fmaxf(mx, fmaxf(fmaxf(v[i].x, v[i].y), fmaxf(v[i].z, v[i].w)));
    }
#pragma unroll
    for (int m = 1; m < 64; m <<= 1) mx = fmaxf(mx, __shfl_xor(mx, m));
    __shared__ float sM[4], sS[4];
    if (!lane) sM[wv] = mx;
    __syncthreads();
    mx = fmaxf(fmaxf(sM[0], sM[1]), fmaxf(sM[2], sM[3]));
    float e[16];
    float sum = 0.f;
#pragma unroll
    for (int i = 0; i < 4; ++i) {
        e[4 * i + 0] = __expf(v[i].x - mx);
        e[4 * i + 1] = __expf(v[i].y - mx);
        e[4 * i + 2] = __expf(v[i].z - mx);
        e[4 * i + 3] = __expf(v[i].w - mx);
        sum += e[4 * i + 0] + e[4 * i + 1] + e[4 * i + 2] + e[4 * i + 3];
    }
#pragma unroll
    for (int m = 1; m < 64; m <<= 1) sum += __shfl_xor(sum, m);
    if (!lane) sS[wv] = sum;
    __syncthreads();
    sum = sS[0] + sS[1] + sS[2] + sS[3];
    float inv = 1.0f / sum;
    u16* prow = P + (size_t)row * 4096;
#pragma unroll
    for (int i = 0; i < 4; ++i) {
        u16x4 o;
        o[0] = f2bf(e[4 * i + 0] * inv);
        o[1] = f2bf(e[4 * i + 1] * inv);
        o[2] = f2bf(e[4 * i + 2] * inv);
        o[3] = f2bf(e[4 * i + 3] * inv);
        *(u16x4*)(prow + (size_t)(t + 256 * i) * 4) = o;
    }
}

// -------------------------------------------------------------- launch ----
extern "C" void kernel_launch(void* const* d_in, const int* in_sizes, int n_in,
                              void* d_out, int out_size, void* d_ws, size_t ws_size,
                              hipStream_t stream)
{
    const float* c   = (const float*)d_in[0];
    const float* s   = (const float*)d_in[1];
    const float* x   = (const float*)d_in[2];
    const float* c_w = (const float*)d_in[3];
    const float* c_b = (const float*)d_in[4];
    const float* s_w = (const float*)d_in[5];
    const float* s_b = (const float*)d_in[6];
    const float* i_w = (const float*)d_in[7];
    const float* i_b = (const float*)d_in[8];
    const float* o_w = (const float*)d_in[9];
    const float* o_b = (const float*)d_in[10];
    float* out = (float*)d_out;
    char* ws = (char*)d_ws;

    const int B = 4, C = 512, N = 4096;
    const size_t NC = (size_t)N * C;          // 2097152
    const size_t W2 = (size_t)C * C;          // 262144

    size_t off = 0;
    auto alloc = [&](size_t bytes) { size_t o = off; off += (bytes + 255) & ~(size_t)255; return o; };

    size_t o_meanC = alloc((size_t)B * C * 4);
    size_t o_rstdC = alloc((size_t)B * C * 4);
    size_t o_meanS = alloc((size_t)B * C * 4);
    size_t o_rstdS = alloc((size_t)B * C * 4);
    size_t o_cwh = alloc(W2 * 2), o_cwl = alloc(W2 * 2);
    size_t o_swh = alloc(W2 * 2), o_swl = alloc(W2 * 2);
    size_t o_iwb = alloc(W2 * 2), o_owb = alloc(W2 * 2);
    size_t o_cnTh = alloc(B * NC * 2);       // these four are contiguous (each
    size_t o_cnTl = alloc(B * NC * 2);       // 16777216B) and are reused as the
    size_t o_snTh = alloc(B * NC * 2);       // per-batch fp32 logits buffer L
    size_t o_snTl = alloc(B * NC * 2);       // (4096*4096*4 = 67108864B exact)
    size_t o_sT   = alloc(B * NC * 2);       // reused as ofT after xf conv
    size_t o_cfTh = alloc(B * NC * 2);
    size_t o_cfTl = alloc(B * NC * 2);
    size_t o_sfTh = alloc(B * NC * 2);
    size_t o_sfTl = alloc(B * NC * 2);
    size_t o_xf   = alloc(B * NC * 2);
    size_t o_P    = alloc((size_t)N * N * 2);

    if (ws_size < off) { // not enough scratch: bail (will fail check loudly)
        hipMemsetAsync(d_out, 0, (size_t)out_size * 4, stream);
        return;
    }

    float* meanC = (float*)(ws + o_meanC);
    float* rstdC = (float*)(ws + o_rstdC);
    float* meanS = (float*)(ws + o_meanS);
    float* rstdS = (float*)(ws + o_rstdS);
    u16* cwh = (u16*)(ws + o_cwh); u16* cwl = (u16*)(ws + o_cwl);
    u16* swh = (u16*)(ws + o_swh); u16* swl = (u16*)(ws + o_swl);
    u16* iwb = (u16*)(ws + o_iwb); u16* owb = (u16*)(ws + o_owb);
    u16* cnTh = (u16*)(ws + o_cnTh); u16* cnTl = (u16*)(ws + o_cnTl);
    u16* snTh = (u16*)(ws + o_snTh); u16* snTl = (u16*)(ws + o_snTl);
    u16* sT   = (u16*)(ws + o_sT);
    u16* cfTh = (u16*)(ws + o_cfTh); u16* cfTl = (u16*)(ws + o_cfTl);
    u16* sfTh = (u16*)(ws + o_sfTh); u16* sfTl = (u16*)(ws + o_sfTl);
    u16* xf   = (u16*)(ws + o_xf);
    u16* Pb   = (u16*)(ws + o_P);
    float* Lbuf = (float*)(ws + o_cnTh);     // alias over cn/sn packs
    u16* ofT = sT;                           // alias over raw-s pack

    // 1) instance-norm stats
    stats_kernel<<<dim3(B * C, 2), 256, 0, stream>>>(c, s, meanC, rstdC, meanS, rstdS);
    // 2) packs: normalized hi/lo transposed [B,N,C], raw s transposed bf16
    pack_kernel<0><<<dim3(N / 32, C / 32, B), dim3(32, 8), 0, stream>>>(c, meanC, rstdC, cnTh, cnTl);
    pack_kernel<0><<<dim3(N / 32, C / 32, B), dim3(32, 8), 0, stream>>>(s, meanS, rstdS, snTh, snTl);
    pack_kernel<1><<<dim3(N / 32, C / 32, B), dim3(32, 8), 0, stream>>>(s, nullptr, nullptr, sT, nullptr);
    // 3) weight packs
    split_hilo<true ><<<dim3((int)(W2 / 256)), 256, 0, stream>>>(c_w, cwh, cwl, (int)W2);
    split_hilo<true ><<<dim3((int)(W2 / 256)), 256, 0, stream>>>(s_w, swh, swl, (int)W2);
    split_hilo<false><<<dim3((int)(W2 / 256)), 256, 0, stream>>>(i_w, iwb, nullptr, (int)W2);
    split_hilo<false><<<dim3((int)(W2 / 256)), 256, 0, stream>>>(o_w, owb, nullptr, (int)W2);
    // 4) cf = c_w @ cn + c_b  -> cfT hi/lo [B,N,C]
    gemm_bt<3, EPI_T_HILO><<<dim3(32, 4, B), 256, 0, stream>>>(
        cwh, cwl, cnTh, cnTl, 512, c_b, nullptr, cfTh, cfTl, nullptr, 512,
        0, (long)NC, (long)NC, 0);
    // 5) sf = s_w @ sn + s_b  -> sfT hi/lo
    gemm_bt<3, EPI_T_HILO><<<dim3(32, 4, B), 256, 0, stream>>>(
        swh, swl, snTh, snTl, 512, s_b, nullptr, sfTh, sfTl, nullptr, 512,
        0, (long)NC, (long)NC, 0);
    // 6) xf = i_w @ s + i_b   -> xf bf16 [B,C,N]
    gemm_bt<1, EPI_PLAIN_BF16><<<dim3(32, 4, B), 256, 0, stream>>>(
        iwb, nullptr, sT, nullptr, 512, i_b, nullptr, xf, nullptr, nullptr, 4096,
        0, (long)NC, (long)NC, 0);
    // 7) per-batch attention
    for (int b = 0; b < B; ++b) {
        // logits L[n,m] = sum_c cfT[n,c]*sfT[m,c]   (fp32, 67MB scratch)
        gemm_bt<3, EPI_F32><<<dim3(32, 32, 1), 256, 0, stream>>>(
            cfTh + (size_t)b * NC, cfTl + (size_t)b * NC,
            sfTh + (size_t)b * NC, sfTl + (size_t)b * NC,
            512, nullptr, Lbuf, nullptr, nullptr, nullptr, 4096, 0, 0, 0, 0);
        // P = softmax_m(L) bf16
        softmax_kernel<<<dim3(N), 256, 0, stream>>>(Lbuf, Pb);
        // of[c,n] = sum_m xf[c,m] * P[n,m]  -> ofT [N,C] bf16
        gemm_bt<1, EPI_T_BF16><<<dim3(32, 4, 1), 256, 0, stream>>>(
            xf + (size_t)b * NC, nullptr, Pb, nullptr, 4096, nullptr,
            nullptr, ofT + (size_t)b * NC, nullptr, nullptr, 512, 0, 0, 0, 0);
    }
    // 8) out = x + o_w @ of + o_b
    gemm_bt<1, EPI_OUT><<<dim3(32, 4, B), 256, 0, stream>>>(
        owb, nullptr, ofT, nullptr, 512, o_b, out, nullptr, nullptr, x, 4096,
        0, (long)NC, (long)NC, (long)NC);
}

// Round 2
// 577.358 us; speedup vs baseline: 1.2851x; 1.2851x over previous
//
#include <hip/hip_runtime.h>

typedef unsigned short u16;
typedef __bf16 bf16x8 __attribute__((ext_vector_type(8)));
typedef float f32x4 __attribute__((ext_vector_type(4)));
typedef u16 u16x4 __attribute__((ext_vector_type(4)));

__device__ __forceinline__ u16 f2bf(float f) {
    unsigned u = __float_as_uint(f);
    unsigned r = (u + 0x7FFFu + ((u >> 16) & 1u)) >> 16;
    return (u16)r;
}
__device__ __forceinline__ float bf2f(u16 h) {
    return __uint_as_float(((unsigned)h) << 16);
}

// ---------------------------------------------------------------- stats ----
__global__ void __launch_bounds__(256) stats_kernel(
    const float* __restrict__ c, const float* __restrict__ s,
    float* __restrict__ mC, float* __restrict__ rC,
    float* __restrict__ mS, float* __restrict__ rS)
{
    const float* src = (blockIdx.y ? s : c) + (size_t)blockIdx.x * 4096;
    int t = threadIdx.x, lane = t & 63, wv = t >> 6;
    const float4* p = (const float4*)src;
    float sum = 0.f, sq = 0.f;
#pragma unroll
    for (int i = 0; i < 4; ++i) {
        float4 v = p[t + 256 * i];
        sum += v.x + v.y + v.z + v.w;
        sq  += v.x * v.x + v.y * v.y + v.z * v.z + v.w * v.w;
    }
#pragma unroll
    for (int m = 1; m < 64; m <<= 1) {
        sum += __shfl_xor(sum, m);
        sq  += __shfl_xor(sq, m);
    }
    __shared__ float sa[4], sb[4];
    if (!lane) { sa[wv] = sum; sb[wv] = sq; }
    __syncthreads();
    if (t == 0) {
        float S = sa[0] + sa[1] + sa[2] + sa[3];
        float Q = sb[0] + sb[1] + sb[2] + sb[3];
        float mean = S * (1.0f / 4096.0f);
        float var = (Q - 4096.0f * mean * mean) * (1.0f / 4095.0f);
        float rstd = rsqrtf(var + 1e-5f);
        if (blockIdx.y) { mS[blockIdx.x] = mean; rS[blockIdx.x] = rstd; }
        else            { mC[blockIdx.x] = mean; rC[blockIdx.x] = rstd; }
    }
}

// ------------------------------------------------------- transpose pack ----
template<int MODE>
__global__ void __launch_bounds__(256) pack_kernel(
    const float* __restrict__ src, const float* __restrict__ mean,
    const float* __restrict__ rstd, u16* __restrict__ dh, u16* __restrict__ dl)
{
    __shared__ float tile[32][33];
    int b = blockIdx.z, n0 = blockIdx.x * 32, c0 = blockIdx.y * 32;
    int tx = threadIdx.x, ty = threadIdx.y;
    const float* sbp = src + ((size_t)b * 512 + c0) * 4096 + n0;
#pragma unroll
    for (int it = 0; it < 4; ++it)
        tile[ty + it * 8][tx] = sbp[(size_t)(ty + it * 8) * 4096 + tx];
    __syncthreads();
    int ch = c0 + tx;
    float mn = 0.f, rs = 1.f;
    if (MODE == 0) { mn = mean[b * 512 + ch]; rs = rstd[b * 512 + ch]; }
    size_t obase = ((size_t)b * 4096 + n0) * 512 + c0;
#pragma unroll
    for (int it = 0; it < 4; ++it) {
        int r = ty + it * 8;
        float v = tile[tx][r];
        if (MODE == 0) v = (v - mn) * rs;
        u16 h = f2bf(v);
        dh[obase + (size_t)r * 512 + tx] = h;
        if (MODE == 0) dl[obase + (size_t)r * 512 + tx] = f2bf(v - bf2f(h));
    }
}

// ------------------------------------------------------------ wt split ----
template<bool LO>
__global__ void __launch_bounds__(256) split_hilo(
    const float* __restrict__ src, u16* __restrict__ h, u16* __restrict__ l, int n)
{
    int i = blockIdx.x * 256 + threadIdx.x;
    if (i < n) {
        float v = src[i];
        u16 a = f2bf(v);
        h[i] = a;
        if (LO) l[i] = f2bf(v - bf2f(a));
    }
}

// ---------------------------------------------------------------- GEMM ----
// C[i,j] = sum_k A[i,k]*B[j,k]  (A:[M,ldk] rowmajor, B:[N,ldk] rowmajor),
// k-loop runs K steps. blockIdx.z offsets A/B/out/resid by aB/bB/oB/rB
// elements (used either as a batch index or as a split-K chunk index).
// NT==3: hi/lo compensated ( AhBh + AhBl + AlBh ).
#define EPI_F32        0
#define EPI_T_HILO     1
#define EPI_PLAIN_BF16 2
#define EPI_T_BF16     3
#define EPI_OUT        4

__device__ __forceinline__ void stage_tile(
    const u16* __restrict__ g, int ldk, int i0, int k0, char* tile, int wv, int lane)
{
#pragma unroll
    for (int cc = 0; cc < 4; ++cc) {
        int chunk = (wv * 4 + cc) * 64 + lane;   // 16B-chunk linear index in tile
        int row  = chunk >> 3;                   // 8 chunks (128B) per row
        int slot = chunk & 7;
        int gc   = slot ^ (row & 7);             // pre-swizzled source column-chunk
        const u16* gp = g + (size_t)(i0 + row) * ldk + (k0 + gc * 8);
        char* lp = tile + (size_t)(wv * 4 + cc) * 1024; // wave-uniform base
        __builtin_amdgcn_global_load_lds(
            (const __attribute__((address_space(1))) unsigned int*)gp,
            (__attribute__((address_space(3))) unsigned int*)lp, 16, 0, 0);
    }
}

template<int NT, int EPI>
__global__ void __launch_bounds__(256) gemm_bt(
    const u16* __restrict__ Ah_, const u16* __restrict__ Al_,
    const u16* __restrict__ Bh_, const u16* __restrict__ Bl_,
    int K, int ldk, const float* __restrict__ bias,
    float* __restrict__ outF_, u16* __restrict__ outH_, u16* __restrict__ outL_,
    const float* __restrict__ resid_, int ldo,
    long aB, long bB, long oB, long rB)
{
    constexpr int NTILES = (NT == 3) ? 4 : 2;
    __shared__ char smem[NTILES * 16384];
    char* sAh = smem;
    char* sBh = smem + 16384;
    char* sAl = smem + 32768;
    char* sBl = smem + 49152;

    int bz = blockIdx.z;
    const u16* A  = Ah_ + (size_t)bz * aB;
    const u16* Bm = Bh_ + (size_t)bz * bB;
    const u16* A2 = (NT == 3) ? Al_ + (size_t)bz * aB : nullptr;
    const u16* B2 = (NT == 3) ? Bl_ + (size_t)bz * bB : nullptr;

    int i0 = blockIdx.y * 128, j0 = blockIdx.x * 128;
    int tid = threadIdx.x, lane = tid & 63, wv = tid >> 6;
    int wr = wv >> 1, wc = wv & 1;
    int r15 = lane & 15, h4 = lane >> 4;

    f32x4 zero = {0.f, 0.f, 0.f, 0.f};
    f32x4 acc[4][4];
#pragma unroll
    for (int m = 0; m < 4; ++m)
#pragma unroll
        for (int n = 0; n < 4; ++n) acc[m][n] = zero;

    for (int k0 = 0; k0 < K; k0 += 64) {
        stage_tile(A, ldk, i0, k0, sAh, wv, lane);
        stage_tile(Bm, ldk, j0, k0, sBh, wv, lane);
        if constexpr (NT == 3) {
            stage_tile(A2, ldk, i0, k0, sAl, wv, lane);
            stage_tile(B2, ldk, j0, k0, sBl, wv, lane);
        }
        asm volatile("s_waitcnt vmcnt(0)" ::: "memory");
        __syncthreads();
#pragma unroll
        for (int ks = 0; ks < 2; ++ks) {
            bf16x8 ah[4], bh[4], al[4], bl[4];
#pragma unroll
            for (int m = 0; m < 4; ++m) {
                int row = wr * 64 + m * 16 + r15;
                int off = row * 128 + (((ks * 4 + h4) ^ (row & 7)) << 4);
                ah[m] = *(const bf16x8*)(sAh + off);
                if constexpr (NT == 3) al[m] = *(const bf16x8*)(sAl + off);
            }
#pragma unroll
            for (int n = 0; n < 4; ++n) {
                int col = wc * 64 + n * 16 + r15;
                int off = col * 128 + (((ks * 4 + h4) ^ (col & 7)) << 4);
                bh[n] = *(const bf16x8*)(sBh + off);
                if constexpr (NT == 3) bl[n] = *(const bf16x8*)(sBl + off);
            }
#pragma unroll
            for (int m = 0; m < 4; ++m)
#pragma unroll
                for (int n = 0; n < 4; ++n) {
                    acc[m][n] = __builtin_amdgcn_mfma_f32_16x16x32_bf16(ah[m], bh[n], acc[m][n], 0, 0, 0);
                    if constexpr (NT == 3) {
                        acc[m][n] = __builtin_amdgcn_mfma_f32_16x16x32_bf16(ah[m], bl[n], acc[m][n], 0, 0, 0);
                        acc[m][n] = __builtin_amdgcn_mfma_f32_16x16x32_bf16(al[m], bh[n], acc[m][n], 0, 0, 0);
                    }
                }
        }
        __syncthreads();
    }

    float* outF = outF_ ? outF_ + (size_t)bz * oB : nullptr;
    u16* outH = outH_ ? outH_ + (size_t)bz * oB : nullptr;
    u16* outL = outL_ ? outL_ + (size_t)bz * oB : nullptr;
    const float* resid = resid_ ? resid_ + (size_t)bz * rB : nullptr;

#pragma unroll
    for (int m = 0; m < 4; ++m)
#pragma unroll
        for (int n = 0; n < 4; ++n) {
            int ibase = i0 + wr * 64 + m * 16 + h4 * 4;
            int j = j0 + wc * 64 + n * 16 + r15;
#pragma unroll
            for (int r = 0; r < 4; ++r) {
                int i = ibase + r;
                float v = acc[m][n][r];
                if constexpr (EPI == EPI_T_HILO || EPI == EPI_PLAIN_BF16 || EPI == EPI_OUT)
                    v += bias[i];
                if constexpr (EPI == EPI_F32) {
                    outF[(size_t)i * ldo + j] = v;
                } else if constexpr (EPI == EPI_T_HILO) {
                    size_t o = (size_t)j * ldo + i;
                    u16 h = f2bf(v);
                    outH[o] = h;
                    outL[o] = f2bf(v - bf2f(h));
                } else if constexpr (EPI == EPI_PLAIN_BF16) {
                    outH[(size_t)i * ldo + j] = f2bf(v);
                } else if constexpr (EPI == EPI_T_BF16) {
                    outH[(size_t)j * ldo + i] = f2bf(v);
                } else { // EPI_OUT
                    outF[(size_t)i * ldo + j] = v + resid[(size_t)i * ldo + j];
                }
            }
        }
}

// ------------------------------------------------ split-K reduce + T ------
// part: [4][512][4096] fp32 (z-planes of of[c,n]); out: ofT [4096,512] bf16
__global__ void __launch_bounds__(256) reduceT_kernel(
    const float* __restrict__ part, u16* __restrict__ ofT)
{
    __shared__ float tile[32][33];
    int n0 = blockIdx.x * 32, c0 = blockIdx.y * 32;
    int tx = threadIdx.x, ty = threadIdx.y;
#pragma unroll
    for (int it = 0; it < 4; ++it) {
        int cc = ty + it * 8;
        size_t idx = (size_t)(c0 + cc) * 4096 + n0 + tx;
        float v = part[idx] + part[idx + 2097152] +
                  part[idx + 2 * 2097152] + part[idx + 3 * 2097152];
        tile[cc][tx] = v;
    }
    __syncthreads();
#pragma unroll
    for (int it = 0; it < 4; ++it) {
        int r = ty + it * 8;
        ofT[(size_t)(n0 + r) * 512 + c0 + tx] = f2bf(tile[tx][r]);
    }
}

// ------------------------------------------------------------- softmax ----
__global__ void __launch_bounds__(256) softmax_kernel(
    const float* __restrict__ L, u16* __restrict__ P)
{
    int row = blockIdx.x;
    int t = threadIdx.x, lane = t & 63, wv = t >> 6;
    const float4* src = (const float4*)(L + (size_t)row * 4096);
    float4 v[4];
    float mx = -3.4e38f;
#pragma unroll
    for (int i = 0; i < 4; ++i) {
        v[i] = src[t + 256 * i];
        mx = fmaxf(mx, fmaxf(fmaxf(v[i].x, v[i].y), fmaxf(v[i].z, v[i].w)));
    }
#pragma unroll
    for (int m = 1; m < 64; m <<= 1) mx = fmaxf(mx, __shfl_xor(mx, m));
    __shared__ float sM[4], sS[4];
    if (!lane) sM[wv] = mx;
    __syncthreads();
    mx = fmaxf(fmaxf(sM[0], sM[1]), fmaxf(sM[2], sM[3]));
    float e[16];
    float sum = 0.f;
#pragma unroll
    for (int i = 0; i < 4; ++i) {
        e[4 * i + 0] = __expf(v[i].x - mx);
        e[4 * i + 1] = __expf(v[i].y - mx);
        e[4 * i + 2] = __expf(v[i].z - mx);
        e[4 * i + 3] = __expf(v[i].w - mx);
        sum += e[4 * i + 0] + e[4 * i + 1] + e[4 * i + 2] + e[4 * i + 3];
    }
#pragma unroll
    for (int m = 1; m < 64; m <<= 1) sum += __shfl_xor(sum, m);
    if (!lane) sS[wv] = sum;
    __syncthreads();
    sum = sS[0] + sS[1] + sS[2] + sS[3];
    float inv = 1.0f / sum;
    u16* prow = P + (size_t)row * 4096;
#pragma unroll
    for (int i = 0; i < 4; ++i) {
        u16x4 o;
        o[0] = f2bf(e[4 * i + 0] * inv);
        o[1] = f2bf(e[4 * i + 1] * inv);
        o[2] = f2bf(e[4 * i + 2] * inv);
        o[3] = f2bf(e[4 * i + 3] * inv);
        *(u16x4*)(prow + (size_t)(t + 256 * i) * 4) = o;
    }
}

// -------------------------------------------------------------- launch ----
extern "C" void kernel_launch(void* const* d_in, const int* in_sizes, int n_in,
                              void* d_out, int out_size, void* d_ws, size_t ws_size,
                              hipStream_t stream)
{
    const float* c   = (const float*)d_in[0];
    const float* s   = (const float*)d_in[1];
    const float* x   = (const float*)d_in[2];
    const float* c_w = (const float*)d_in[3];
    const float* c_b = (const float*)d_in[4];
    const float* s_w = (const float*)d_in[5];
    const float* s_b = (const float*)d_in[6];
    const float* i_w = (const float*)d_in[7];
    const float* i_b = (const float*)d_in[8];
    const float* o_w = (const float*)d_in[9];
    const float* o_b = (const float*)d_in[10];
    float* out = (float*)d_out;
    char* ws = (char*)d_ws;

    const int B = 4, C = 512, N = 4096;
    const size_t NC = (size_t)N * C;          // 2097152
    const size_t W2 = (size_t)C * C;          // 262144

    size_t off = 0;
    auto alloc = [&](size_t bytes) { size_t o = off; off += (bytes + 255) & ~(size_t)255; return o; };

    size_t o_meanC = alloc((size_t)B * C * 4);
    size_t o_rstdC = alloc((size_t)B * C * 4);
    size_t o_meanS = alloc((size_t)B * C * 4);
    size_t o_rstdS = alloc((size_t)B * C * 4);
    size_t o_cwh = alloc(W2 * 2), o_cwl = alloc(W2 * 2);
    size_t o_swh = alloc(W2 * 2), o_swl = alloc(W2 * 2);
    size_t o_iwb = alloc(W2 * 2), o_owb = alloc(W2 * 2);
    size_t o_cnTh = alloc(B * NC * 2);       // these four are contiguous (each
    size_t o_cnTl = alloc(B * NC * 2);       // 16777216B) and are reused as the
    size_t o_snTh = alloc(B * NC * 2);       // per-batch fp32 logits buffer L
    size_t o_snTl = alloc(B * NC * 2);       // (4096*4096*4B) and, after softmax,
    size_t o_sT   = alloc(B * NC * 2);       // as split-K PV partials (33.5MB).
    size_t o_cfTh = alloc(B * NC * 2);       // o_sT reused as ofT after xf conv.
    size_t o_cfTl = alloc(B * NC * 2);
    size_t o_sfTh = alloc(B * NC * 2);
    size_t o_sfTl = alloc(B * NC * 2);
    size_t o_xf   = alloc(B * NC * 2);
    size_t o_P    = alloc((size_t)N * N * 2);

    if (ws_size < off) { // not enough scratch: bail (will fail check loudly)
        hipMemsetAsync(d_out, 0, (size_t)out_size * 4, stream);
        return;
    }

    float* meanC = (float*)(ws + o_meanC);
    float* rstdC = (float*)(ws + o_rstdC);
    float* meanS = (float*)(ws + o_meanS);
    float* rstdS = (float*)(ws + o_rstdS);
    u16* cwh = (u16*)(ws + o_cwh); u16* cwl = (u16*)(ws + o_cwl);
    u16* swh = (u16*)(ws + o_swh); u16* swl = (u16*)(ws + o_swl);
    u16* iwb = (u16*)(ws + o_iwb); u16* owb = (u16*)(ws + o_owb);
    u16* cnTh = (u16*)(ws + o_cnTh); u16* cnTl = (u16*)(ws + o_cnTl);
    u16* snTh = (u16*)(ws + o_snTh); u16* snTl = (u16*)(ws + o_snTl);
    u16* sT   = (u16*)(ws + o_sT);
    u16* cfTh = (u16*)(ws + o_cfTh); u16* cfTl = (u16*)(ws + o_cfTl);
    u16* sfTh = (u16*)(ws + o_sfTh); u16* sfTl = (u16*)(ws + o_sfTl);
    u16* xf   = (u16*)(ws + o_xf);
    u16* Pb   = (u16*)(ws + o_P);
    float* Lbuf = (float*)(ws + o_cnTh);     // alias over cn/sn packs (64MB)
    u16* ofT = sT;                           // alias over raw-s pack

    // 1) instance-norm stats
    stats_kernel<<<dim3(B * C, 2), 256, 0, stream>>>(c, s, meanC, rstdC, meanS, rstdS);
    // 2) packs: normalized hi/lo transposed [B,N,C], raw s transposed bf16
    pack_kernel<0><<<dim3(N / 32, C / 32, B), dim3(32, 8), 0, stream>>>(c, meanC, rstdC, cnTh, cnTl);
    pack_kernel<0><<<dim3(N / 32, C / 32, B), dim3(32, 8), 0, stream>>>(s, meanS, rstdS, snTh, snTl);
    pack_kernel<1><<<dim3(N / 32, C / 32, B), dim3(32, 8), 0, stream>>>(s, nullptr, nullptr, sT, nullptr);
    // 3) weight packs
    split_hilo<true ><<<dim3((int)(W2 / 256)), 256, 0, stream>>>(c_w, cwh, cwl, (int)W2);
    split_hilo<true ><<<dim3((int)(W2 / 256)), 256, 0, stream>>>(s_w, swh, swl, (int)W2);
    split_hilo<false><<<dim3((int)(W2 / 256)), 256, 0, stream>>>(i_w, iwb, nullptr, (int)W2);
    split_hilo<false><<<dim3((int)(W2 / 256)), 256, 0, stream>>>(o_w, owb, nullptr, (int)W2);
    // 4) cf = c_w @ cn + c_b  -> cfT hi/lo [B,N,C]
    gemm_bt<3, EPI_T_HILO><<<dim3(32, 4, B), 256, 0, stream>>>(
        cwh, cwl, cnTh, cnTl, 512, 512, c_b, nullptr, cfTh, cfTl, nullptr, 512,
        0, (long)NC, (long)NC, 0);
    // 5) sf = s_w @ sn + s_b  -> sfT hi/lo
    gemm_bt<3, EPI_T_HILO><<<dim3(32, 4, B), 256, 0, stream>>>(
        swh, swl, snTh, snTl, 512, 512, s_b, nullptr, sfTh, sfTl, nullptr, 512,
        0, (long)NC, (long)NC, 0);
    // 6) xf = i_w @ s + i_b   -> xf bf16 [B,C,N]
    gemm_bt<1, EPI_PLAIN_BF16><<<dim3(32, 4, B), 256, 0, stream>>>(
        iwb, nullptr, sT, nullptr, 512, 512, i_b, nullptr, xf, nullptr, nullptr, 4096,
        0, (long)NC, (long)NC, 0);
    // 7) per-batch attention
    for (int b = 0; b < B; ++b) {
        // logits L[n,m] = sum_c cfT[n,c]*sfT[m,c]   (fp32, 64MB scratch)
        gemm_bt<3, EPI_F32><<<dim3(32, 32, 1), 256, 0, stream>>>(
            cfTh + (size_t)b * NC, cfTl + (size_t)b * NC,
            sfTh + (size_t)b * NC, sfTl + (size_t)b * NC,
            512, 512, nullptr, Lbuf, nullptr, nullptr, nullptr, 4096, 0, 0, 0, 0);
        // P = softmax_m(L) bf16
        softmax_kernel<<<dim3(N), 256, 0, stream>>>(Lbuf, Pb);
        // of[c,n] = sum_m xf[c,m] * P[n,m] — split-K over 4 chunks of 1024,
        // fp32 partials [z][512][4096] into the (now dead) L region.
        gemm_bt<1, EPI_F32><<<dim3(32, 4, 4), 256, 0, stream>>>(
            xf + (size_t)b * NC, nullptr, Pb, nullptr, 1024, 4096, nullptr,
            Lbuf, nullptr, nullptr, nullptr, 4096,
            1024L, 1024L, (long)NC, 0);
        // reduce 4 partials + transpose -> ofT [N,C] bf16
        reduceT_kernel<<<dim3(128, 16), dim3(32, 8), 0, stream>>>(
            Lbuf, ofT + (size_t)b * NC);
    }
    // 8) out = x + o_w @ of + o_b
    gemm_bt<1, EPI_OUT><<<dim3(32, 4, B), 256, 0, stream>>>(
        owb, nullptr, ofT, nullptr, 512, 512, o_b, out, nullptr, nullptr, x, 4096,
        0, (long)NC, (long)NC, (long)NC);
}

// Round 3
// 436.135 us; speedup vs baseline: 1.7013x; 1.3238x over previous
//
#include <hip/hip_runtime.h>

typedef unsigned short u16;
typedef _Float16 f16x8 __attribute__((ext_vector_type(8)));
typedef float f32x4 __attribute__((ext_vector_type(4)));
typedef u16 u16x4 __attribute__((ext_vector_type(4)));

__device__ __forceinline__ u16 f2h(float f) {
    _Float16 h = (_Float16)f;
    return __builtin_bit_cast(u16, h);
}

// ---------------------------------------------------------------- stats ----
__global__ void __launch_bounds__(256) stats_kernel(
    const float* __restrict__ c, const float* __restrict__ s,
    float* __restrict__ mC, float* __restrict__ rC,
    float* __restrict__ mS, float* __restrict__ rS)
{
    const float* src = (blockIdx.y ? s : c) + (size_t)blockIdx.x * 4096;
    int t = threadIdx.x, lane = t & 63, wv = t >> 6;
    const float4* p = (const float4*)src;
    float sum = 0.f, sq = 0.f;
#pragma unroll
    for (int i = 0; i < 4; ++i) {
        float4 v = p[t + 256 * i];
        sum += v.x + v.y + v.z + v.w;
        sq  += v.x * v.x + v.y * v.y + v.z * v.z + v.w * v.w;
    }
#pragma unroll
    for (int m = 1; m < 64; m <<= 1) {
        sum += __shfl_xor(sum, m);
        sq  += __shfl_xor(sq, m);
    }
    __shared__ float sa[4], sb[4];
    if (!lane) { sa[wv] = sum; sb[wv] = sq; }
    __syncthreads();
    if (t == 0) {
        float S = sa[0] + sa[1] + sa[2] + sa[3];
        float Q = sb[0] + sb[1] + sb[2] + sb[3];
        float mean = S * (1.0f / 4096.0f);
        float var = (Q - 4096.0f * mean * mean) * (1.0f / 4095.0f);
        float rstd = rsqrtf(var + 1e-5f);
        if (blockIdx.y) { mS[blockIdx.x] = mean; rS[blockIdx.x] = rstd; }
        else            { mC[blockIdx.x] = mean; rC[blockIdx.x] = rstd; }
    }
}

// ------------------------------------------------------- transpose pack ----
// [B,C,N] fp32 -> [B,N,C] f16. MODE 0: normalized only (dh).
// MODE 2: normalized (dh) + raw (dl) in one pass (for tensor s).
template<int MODE>
__global__ void __launch_bounds__(256) pack_kernel(
    const float* __restrict__ src, const float* __restrict__ mean,
    const float* __restrict__ rstd, u16* __restrict__ dh, u16* __restrict__ dl)
{
    __shared__ float tile[32][33];
    int b = blockIdx.z, n0 = blockIdx.x * 32, c0 = blockIdx.y * 32;
    int tx = threadIdx.x, ty = threadIdx.y;
    const float* sbp = src + ((size_t)b * 512 + c0) * 4096 + n0;
#pragma unroll
    for (int it = 0; it < 4; ++it)
        tile[ty + it * 8][tx] = sbp[(size_t)(ty + it * 8) * 4096 + tx];
    __syncthreads();
    int ch = c0 + tx;
    float mn = mean[b * 512 + ch];
    float rs = rstd[b * 512 + ch];
    size_t obase = ((size_t)b * 4096 + n0) * 512 + c0;
#pragma unroll
    for (int it = 0; it < 4; ++it) {
        int r = ty + it * 8;
        float v = tile[tx][r];
        size_t o = obase + (size_t)r * 512 + tx;
        dh[o] = f2h((v - mn) * rs);
        if (MODE == 2) dl[o] = f2h(v);
    }
}

// ------------------------------------------------------------ wt pack ----
__global__ void __launch_bounds__(256) split_f16(
    const float* __restrict__ src, u16* __restrict__ h, int n)
{
    int i = blockIdx.x * 256 + threadIdx.x;
    if (i < n) h[i] = f2h(src[i]);
}

// ---------------------------------------------------------------- GEMM ----
// C[i,j] = sum_k A[i,k]*B[j,k]  (A:[M,ldk] rowmajor, B:[N,ldk] rowmajor),
// k-loop runs K steps. blockIdx.z offsets A/B/out/resid by aB/bB/oB/rB
// elements (batch index or split-K chunk index).
#define EPI_F32       0
#define EPI_T_F16     1
#define EPI_PLAIN_F16 2
#define EPI_OUT       3

__device__ __forceinline__ void stage_tile(
    const u16* __restrict__ g, int ldk, int i0, int k0, char* tile, int wv, int lane)
{
#pragma unroll
    for (int cc = 0; cc < 4; ++cc) {
        int chunk = (wv * 4 + cc) * 64 + lane;   // 16B-chunk linear index in tile
        int row  = chunk >> 3;                   // 8 chunks (128B) per row
        int slot = chunk & 7;
        int gc   = slot ^ (row & 7);             // pre-swizzled source column-chunk
        const u16* gp = g + (size_t)(i0 + row) * ldk + (k0 + gc * 8);
        char* lp = tile + (size_t)(wv * 4 + cc) * 1024; // wave-uniform base
        __builtin_amdgcn_global_load_lds(
            (const __attribute__((address_space(1))) unsigned int*)gp,
            (__attribute__((address_space(3))) unsigned int*)lp, 16, 0, 0);
    }
}

template<int EPI>
__global__ void __launch_bounds__(256) gemm_bt(
    const u16* __restrict__ A_, const u16* __restrict__ B_,
    int K, int ldk, const float* __restrict__ bias,
    float* __restrict__ outF_, u16* __restrict__ outH_,
    const float* __restrict__ resid_, int ldo,
    long aB, long bB, long oB, long rB)
{
    __shared__ char smem[32768];
    char* sA = smem;
    char* sB = smem + 16384;

    int bz = blockIdx.z;
    const u16* A  = A_ + (size_t)bz * aB;
    const u16* Bm = B_ + (size_t)bz * bB;

    int i0 = blockIdx.y * 128, j0 = blockIdx.x * 128;
    int tid = threadIdx.x, lane = tid & 63, wv = tid >> 6;
    int wr = wv >> 1, wc = wv & 1;
    int r15 = lane & 15, h4 = lane >> 4;

    f32x4 zero = {0.f, 0.f, 0.f, 0.f};
    f32x4 acc[4][4];
#pragma unroll
    for (int m = 0; m < 4; ++m)
#pragma unroll
        for (int n = 0; n < 4; ++n) acc[m][n] = zero;

    for (int k0 = 0; k0 < K; k0 += 64) {
        stage_tile(A, ldk, i0, k0, sA, wv, lane);
        stage_tile(Bm, ldk, j0, k0, sB, wv, lane);
        asm volatile("s_waitcnt vmcnt(0)" ::: "memory");
        __syncthreads();
#pragma unroll
        for (int ks = 0; ks < 2; ++ks) {
            f16x8 a[4], b[4];
#pragma unroll
            for (int m = 0; m < 4; ++m) {
                int row = wr * 64 + m * 16 + r15;
                int off = row * 128 + (((ks * 4 + h4) ^ (row & 7)) << 4);
                a[m] = *(const f16x8*)(sA + off);
            }
#pragma unroll
            for (int n = 0; n < 4; ++n) {
                int col = wc * 64 + n * 16 + r15;
                int off = col * 128 + (((ks * 4 + h4) ^ (col & 7)) << 4);
                b[n] = *(const f16x8*)(sB + off);
            }
#pragma unroll
            for (int m = 0; m < 4; ++m)
#pragma unroll
                for (int n = 0; n < 4; ++n)
                    acc[m][n] = __builtin_amdgcn_mfma_f32_16x16x32_f16(a[m], b[n], acc[m][n], 0, 0, 0);
        }
        __syncthreads();
    }

    float* outF = outF_ ? outF_ + (size_t)bz * oB : nullptr;
    u16* outH = outH_ ? outH_ + (size_t)bz * oB : nullptr;
    const float* resid = resid_ ? resid_ + (size_t)bz * rB : nullptr;

#pragma unroll
    for (int m = 0; m < 4; ++m)
#pragma unroll
        for (int n = 0; n < 4; ++n) {
            int ibase = i0 + wr * 64 + m * 16 + h4 * 4;
            int j = j0 + wc * 64 + n * 16 + r15;
#pragma unroll
            for (int r = 0; r < 4; ++r) {
                int i = ibase + r;
                float v = acc[m][n][r];
                if constexpr (EPI == EPI_T_F16 || EPI == EPI_PLAIN_F16 || EPI == EPI_OUT)
                    v += bias[i];
                if constexpr (EPI == EPI_F32) {
                    outF[(size_t)i * ldo + j] = v;
                } else if constexpr (EPI == EPI_T_F16) {
                    outH[(size_t)j * ldo + i] = f2h(v);
                } else if constexpr (EPI == EPI_PLAIN_F16) {
                    outH[(size_t)i * ldo + j] = f2h(v);
                } else { // EPI_OUT
                    outF[(size_t)i * ldo + j] = v + resid[(size_t)i * ldo + j];
                }
            }
        }
}

// ------------------------------------------------ split-K reduce + T ------
// part: [4][512][4096] fp32 (z-planes of of[c,n]); out: ofT [4096,512] f16
__global__ void __launch_bounds__(256) reduceT_kernel(
    const float* __restrict__ part, u16* __restrict__ ofT)
{
    __shared__ float tile[32][33];
    int n0 = blockIdx.x * 32, c0 = blockIdx.y * 32;
    int tx = threadIdx.x, ty = threadIdx.y;
#pragma unroll
    for (int it = 0; it < 4; ++it) {
        int cc = ty + it * 8;
        size_t idx = (size_t)(c0 + cc) * 4096 + n0 + tx;
        float v = part[idx] + part[idx + 2097152] +
                  part[idx + 2 * 2097152] + part[idx + 3 * 2097152];
        tile[cc][tx] = v;
    }
    __syncthreads();
#pragma unroll
    for (int it = 0; it < 4; ++it) {
        int r = ty + it * 8;
        ofT[(size_t)(n0 + r) * 512 + c0 + tx] = f2h(tile[tx][r]);
    }
}

// ------------------------------------------------------------- softmax ----
__global__ void __launch_bounds__(256) softmax_kernel(
    const float* __restrict__ L, u16* __restrict__ P)
{
    int row = blockIdx.x;
    int t = threadIdx.x, lane = t & 63, wv = t >> 6;
    const float4* src = (const float4*)(L + (size_t)row * 4096);
    float4 v[4];
    float mx = -3.4e38f;
#pragma unroll
    for (int i = 0; i < 4; ++i) {
        v[i] = src[t + 256 * i];
        mx = fmaxf(mx, fmaxf(fmaxf(v[i].x, v[i].y), fmaxf(v[i].z, v[i].w)));
    }
#pragma unroll
    for (int m = 1; m < 64; m <<= 1) mx = fmaxf(mx, __shfl_xor(mx, m));
    __shared__ float sM[4], sS[4];
    if (!lane) sM[wv] = mx;
    __syncthreads();
    mx = fmaxf(fmaxf(sM[0], sM[1]), fmaxf(sM[2], sM[3]));
    float e[16];
    float sum = 0.f;
#pragma unroll
    for (int i = 0; i < 4; ++i) {
        e[4 * i + 0] = __expf(v[i].x - mx);
        e[4 * i + 1] = __expf(v[i].y - mx);
        e[4 * i + 2] = __expf(v[i].z - mx);
        e[4 * i + 3] = __expf(v[i].w - mx);
        sum += e[4 * i + 0] + e[4 * i + 1] + e[4 * i + 2] + e[4 * i + 3];
    }
#pragma unroll
    for (int m = 1; m < 64; m <<= 1) sum += __shfl_xor(sum, m);
    if (!lane) sS[wv] = sum;
    __syncthreads();
    sum = sS[0] + sS[1] + sS[2] + sS[3];
    float inv = 1.0f / sum;
    u16* prow = P + (size_t)row * 4096;
#pragma unroll
    for (int i = 0; i < 4; ++i) {
        u16x4 o;
        o[0] = f2h(e[4 * i + 0] * inv);
        o[1] = f2h(e[4 * i + 1] * inv);
        o[2] = f2h(e[4 * i + 2] * inv);
        o[3] = f2h(e[4 * i + 3] * inv);
        *(u16x4*)(prow + (size_t)(t + 256 * i) * 4) = o;
    }
}

// -------------------------------------------------------------- launch ----
extern "C" void kernel_launch(void* const* d_in, const int* in_sizes, int n_in,
                              void* d_out, int out_size, void* d_ws, size_t ws_size,
                              hipStream_t stream)
{
    const float* c   = (const float*)d_in[0];
    const float* s   = (const float*)d_in[1];
    const float* x   = (const float*)d_in[2];
    const float* c_w = (const float*)d_in[3];
    const float* c_b = (const float*)d_in[4];
    const float* s_w = (const float*)d_in[5];
    const float* s_b = (const float*)d_in[6];
    const float* i_w = (const float*)d_in[7];
    const float* i_b = (const float*)d_in[8];
    const float* o_w = (const float*)d_in[9];
    const float* o_b = (const float*)d_in[10];
    float* out = (float*)d_out;
    char* ws = (char*)d_ws;

    const int B = 4, C = 512, N = 4096;
    const size_t NC = (size_t)N * C;          // 2097152
    const size_t W2 = (size_t)C * C;          // 262144

    size_t off = 0;
    auto alloc = [&](size_t bytes) { size_t o = off; off += (bytes + 255) & ~(size_t)255; return o; };

    size_t o_meanC = alloc((size_t)B * C * 4);
    size_t o_rstdC = alloc((size_t)B * C * 4);
    size_t o_meanS = alloc((size_t)B * C * 4);
    size_t o_rstdS = alloc((size_t)B * C * 4);
    size_t o_cw = alloc(W2 * 2);
    size_t o_sw = alloc(W2 * 2);
    size_t o_iw = alloc(W2 * 2);
    size_t o_ow = alloc(W2 * 2);
    size_t o_cnT = alloc(B * NC * 2);
    size_t o_snT = alloc(B * NC * 2);
    size_t o_sT  = alloc(B * NC * 2);        // reused as ofT after xf conv
    size_t o_cfT = alloc(B * NC * 2);
    size_t o_sfT = alloc(B * NC * 2);
    size_t o_xf  = alloc(B * NC * 2);
    size_t o_P   = alloc((size_t)N * N * 2);
    size_t o_L   = alloc((size_t)N * N * 4); // logits fp32; reused for PV partials

    if (ws_size < off) { // not enough scratch: bail (will fail check loudly)
        hipMemsetAsync(d_out, 0, (size_t)out_size * 4, stream);
        return;
    }

    float* meanC = (float*)(ws + o_meanC);
    float* rstdC = (float*)(ws + o_rstdC);
    float* meanS = (float*)(ws + o_meanS);
    float* rstdS = (float*)(ws + o_rstdS);
    u16* cw = (u16*)(ws + o_cw);
    u16* sw = (u16*)(ws + o_sw);
    u16* iw = (u16*)(ws + o_iw);
    u16* ow = (u16*)(ws + o_ow);
    u16* cnT = (u16*)(ws + o_cnT);
    u16* snT = (u16*)(ws + o_snT);
    u16* sT  = (u16*)(ws + o_sT);
    u16* cfT = (u16*)(ws + o_cfT);
    u16* sfT = (u16*)(ws + o_sfT);
    u16* xf  = (u16*)(ws + o_xf);
    u16* Pb  = (u16*)(ws + o_P);
    float* Lbuf = (float*)(ws + o_L);
    u16* ofT = sT;                           // alias over raw-s pack

    // 1) instance-norm stats
    stats_kernel<<<dim3(B * C, 2), 256, 0, stream>>>(c, s, meanC, rstdC, meanS, rstdS);
    // 2) packs: c -> cnT (norm); s -> snT (norm) + sT (raw) in one pass
    pack_kernel<0><<<dim3(N / 32, C / 32, B), dim3(32, 8), 0, stream>>>(c, meanC, rstdC, cnT, nullptr);
    pack_kernel<2><<<dim3(N / 32, C / 32, B), dim3(32, 8), 0, stream>>>(s, meanS, rstdS, snT, sT);
    // 3) weight packs
    split_f16<<<dim3((int)(W2 / 256)), 256, 0, stream>>>(c_w, cw, (int)W2);
    split_f16<<<dim3((int)(W2 / 256)), 256, 0, stream>>>(s_w, sw, (int)W2);
    split_f16<<<dim3((int)(W2 / 256)), 256, 0, stream>>>(i_w, iw, (int)W2);
    split_f16<<<dim3((int)(W2 / 256)), 256, 0, stream>>>(o_w, ow, (int)W2);
    // 4) cf = c_w @ cn + c_b  -> cfT [B,N,C] f16
    gemm_bt<EPI_T_F16><<<dim3(32, 4, B), 256, 0, stream>>>(
        cw, cnT, 512, 512, c_b, nullptr, cfT, nullptr, 512,
        0, (long)NC, (long)NC, 0);
    // 5) sf = s_w @ sn + s_b  -> sfT
    gemm_bt<EPI_T_F16><<<dim3(32, 4, B), 256, 0, stream>>>(
        sw, snT, 512, 512, s_b, nullptr, sfT, nullptr, 512,
        0, (long)NC, (long)NC, 0);
    // 6) xf = i_w @ s + i_b   -> xf f16 [B,C,N]
    gemm_bt<EPI_PLAIN_F16><<<dim3(32, 4, B), 256, 0, stream>>>(
        iw, sT, 512, 512, i_b, nullptr, xf, nullptr, 4096,
        0, (long)NC, (long)NC, 0);
    // 7) per-batch attention
    for (int b = 0; b < B; ++b) {
        // logits L[n,m] = sum_c cfT[n,c]*sfT[m,c]   (fp32, 64MB scratch)
        gemm_bt<EPI_F32><<<dim3(32, 32, 1), 256, 0, stream>>>(
            cfT + (size_t)b * NC, sfT + (size_t)b * NC,
            512, 512, nullptr, Lbuf, nullptr, nullptr, 4096, 0, 0, 0, 0);
        // P = softmax_m(L) f16
        softmax_kernel<<<dim3(N), 256, 0, stream>>>(Lbuf, Pb);
        // of[c,n] = sum_m xf[c,m] * P[n,m] — split-K over 4 chunks of 1024,
        // fp32 partials [z][512][4096] into the (now dead) L region.
        gemm_bt<EPI_F32><<<dim3(32, 4, 4), 256, 0, stream>>>(
            xf + (size_t)b * NC, Pb, 1024, 4096, nullptr,
            Lbuf, nullptr, nullptr, 4096,
            1024L, 1024L, (long)NC, 0);
        // reduce 4 partials + transpose -> ofT [N,C] f16
        reduceT_kernel<<<dim3(128, 16), dim3(32, 8), 0, stream>>>(
            Lbuf, ofT + (size_t)b * NC);
    }
    // 8) out = x + o_w @ of + o_b
    gemm_bt<EPI_OUT><<<dim3(32, 4, B), 256, 0, stream>>>(
        ow, ofT, 512, 512, o_b, out, nullptr, x, 4096,
        0, (long)NC, (long)NC, (long)NC);
}